// Round 4
// baseline (3990.799 us; speedup 1.0000x reference)
//
#include <hip/hip_runtime.h>

#define CIN   8
#define COUT  16
#define HH    56
#define WW    56
#define SS    784                  // 28*28 symbolic vector per pixel
#define PLANE (HH * WW * SS)       // 2458624 floats per channel plane
#define SYM_OUT_SZ (COUT * PLANE)  // 39337984

// Block tile: 4 rows x 8 cols of pixels, JC=8 f32x2 units of the 784-vector.
#define TH 4
#define TW 8
#define HALO_H (TH + 2)            // 6
#define HALO_W (TW + 2)            // 10
#define NHALO  (HALO_H * HALO_W)   // 60 halo pixels
#define JC 8                       // f32x2 units per block j-chunk (16 floats)
#define NCHUNK (392 / JC)          // 49 chunks
#define NITEMS (NHALO * JC)        // 480 staging items per ci

typedef float f32x2 __attribute__((ext_vector_type(2)));
typedef float f32x4 __attribute__((ext_vector_type(4)));

#if defined(__has_builtin)
#if __has_builtin(__builtin_elementwise_fma)
#define PK_FMA(a, b, c) __builtin_elementwise_fma((a), (b), (c))
#endif
#endif
#ifndef PK_FMA
#define PK_FMA(a, b, c) ((a) * (b) + (c))
#endif

// Prep: transposed weight table in workspace.
// wtr[tap*32 + co]      = 0.5 * w[co][tap]
// wtr[tap*32 + 16 + co] = 0.5 * |w[co][tap]|   (tap = ci*9 + dh*3 + dw)
__global__ __launch_bounds__(256) void ibp_prep_w(
    const float* __restrict__ wgt, float* __restrict__ wtr)
{
    const int i = blockIdx.x * 256 + threadIdx.x;
    if (i >= 72 * 16) return;
    const int tap = i >> 4, co = i & 15;
    const int ci = tap / 9, r = tap - ci * 9;
    const float w = wgt[(co * CIN + ci) * 9 + r];
    wtr[tap * 32 + co]      = 0.5f * w;
    wtr[tap * 32 + 16 + co] = 0.5f * fabsf(w);
}

// Main symbolic-bound conv with LDS halo staging.
//   lx_out = A + B,  ux_out = A - B,  where per tap:
//   A += 0.5*w*(l+u), B += 0.5*|w|*(l-u)
// Per ci: the 6x10 pixel halo (x 8 f32x2 j-units) is staged in LDS as
// interleaved {s.x,s.y,d.x,d.y} f32x4 -> each tap is ONE ds_read_b128 with a
// compile-time offset + 32 pk_fma. s,d computed once per element (not 9x).
// LDS is double-buffered over ci; next-ci global loads are issued into regs
// before the current-ci compute so HBM/L2 latency hides under 288 FMAs.
__global__ __launch_bounds__(256) void ibp_conv_sym(
    const float* __restrict__ lx, const float* __restrict__ ux,
    const float* __restrict__ wtr,
    float* __restrict__ lx_out, float* __restrict__ ux_out)
{
    __shared__ f32x4 sd[2][NITEMS];   // 2 x 480 x 16B = 15360 B

    const int t  = threadIdx.x;
    const int b  = blockIdx.x;
    const int jc = b % NCHUNK;
    const int rb = b / NCHUNK;
    const int hb = rb % (HH / TH);
    const int wb = rb / (HH / TH);
    const int h0 = hb * TH, w0 = wb * TW;
    const int jbase = jc * (JC * 2);     // float offset within a pixel's 784

    // Compute-role coords: one (pixel, j2) output column per thread.
    const int j2  = t & 7;
    const int pix = t >> 3;              // 0..31
    const int ph  = pix >> 3;            // 0..3
    const int pw  = pix & 7;             // 0..7

    // Staging-role: item0 = t, item1 = t + 256 (active for t < 224).
    // Precompute validity + global float offsets once (ci adds ci*PLANE).
    int v0, v1 = 0;
    size_t off0, off1 = 0;
    {
        const int sp = t >> 3, sj = t & 7;
        const int shh = sp / HALO_W, sww = sp % HALO_W;
        const int gh = h0 - 1 + shh, gw = w0 - 1 + sww;
        v0 = ((unsigned)gh < (unsigned)HH) & ((unsigned)gw < (unsigned)WW);
        off0 = v0 ? ((size_t)(gh * WW + gw) * SS + jbase + sj * 2) : 0;
    }
    if (t < NITEMS - 256) {
        const int it = t + 256;
        const int sp = it >> 3, sj = it & 7;
        const int shh = sp / HALO_W, sww = sp % HALO_W;
        const int gh = h0 - 1 + shh, gw = w0 - 1 + sww;
        v1 = ((unsigned)gh < (unsigned)HH) & ((unsigned)gw < (unsigned)WW);
        off1 = v1 ? ((size_t)(gh * WW + gw) * SS + jbase + sj * 2) : 0;
    }

    // Accumulators: one f32x2 per cout for A and B.
    f32x2 A[COUT], B[COUT];
    #pragma unroll
    for (int co = 0; co < COUT; ++co) { A[co] = (f32x2)0.f; B[co] = (f32x2)0.f; }

    // Prologue: stage ci=0 into buffer 0.
    {
        f32x2 l0 = *(const f32x2*)(lx + off0);
        f32x2 u0 = *(const f32x2*)(ux + off0);
        if (!v0) { l0 = (f32x2)0.f; u0 = (f32x2)0.f; }
        f32x4 o0; o0.x = l0.x + u0.x; o0.y = l0.y + u0.y;
                  o0.z = l0.x - u0.x; o0.w = l0.y - u0.y;
        sd[0][t] = o0;
        if (t < NITEMS - 256) {
            f32x2 l1 = *(const f32x2*)(lx + off1);
            f32x2 u1 = *(const f32x2*)(ux + off1);
            if (!v1) { l1 = (f32x2)0.f; u1 = (f32x2)0.f; }
            f32x4 o1; o1.x = l1.x + u1.x; o1.y = l1.y + u1.y;
                      o1.z = l1.x - u1.x; o1.w = l1.y - u1.y;
            sd[0][t + 256] = o1;
        }
    }
    __syncthreads();

    const int lbase = (ph * HALO_W + pw) * JC + j2;

    #pragma unroll
    for (int ci = 0; ci < CIN; ++ci) {
        // Issue next-ci loads early (regs) so latency hides under compute.
        f32x2 nl0 = (f32x2)0.f, nu0 = (f32x2)0.f;
        f32x2 nl1 = (f32x2)0.f, nu1 = (f32x2)0.f;
        if (ci + 1 < CIN) {
            const float* lp = lx + (size_t)(ci + 1) * PLANE;
            const float* up = ux + (size_t)(ci + 1) * PLANE;
            nl0 = *(const f32x2*)(lp + off0);
            nu0 = *(const f32x2*)(up + off0);
            if (t < NITEMS - 256) {
                nl1 = *(const f32x2*)(lp + off1);
                nu1 = *(const f32x2*)(up + off1);
            }
        }

        // Compute 9 taps from the current buffer.
        const f32x4* bufp = sd[ci & 1];
        const float* wp = wtr + ci * 9 * 32;
        #pragma unroll
        for (int dh = 0; dh < 3; ++dh) {
            #pragma unroll
            for (int dw = 0; dw < 3; ++dw) {
                const f32x4 v = bufp[lbase + (dh * HALO_W + dw) * JC];
                f32x2 s; s.x = v.x; s.y = v.y;
                f32x2 d; d.x = v.z; d.y = v.w;
                const float* wt = wp + (dh * 3 + dw) * 32;
                #pragma unroll
                for (int co = 0; co < COUT; ++co) {
                    const float wa = wt[co];        // 0.5*w    (SGPR)
                    const float wb = wt[16 + co];   // 0.5*|w|  (SGPR)
                    const f32x2 wa2 = {wa, wa};
                    const f32x2 wb2 = {wb, wb};
                    A[co] = PK_FMA(wa2, s, A[co]);
                    B[co] = PK_FMA(wb2, d, B[co]);
                }
            }
        }

        // Write next buffer and sync (single barrier per ci; the buffer being
        // written was last read in ci-1, protected by that iteration's barrier).
        if (ci + 1 < CIN) {
            f32x4* dst = sd[(ci + 1) & 1];
            if (!v0) { nl0 = (f32x2)0.f; nu0 = (f32x2)0.f; }
            f32x4 o0; o0.x = nl0.x + nu0.x; o0.y = nl0.y + nu0.y;
                      o0.z = nl0.x - nu0.x; o0.w = nl0.y - nu0.y;
            dst[t] = o0;
            if (t < NITEMS - 256) {
                if (!v1) { nl1 = (f32x2)0.f; nu1 = (f32x2)0.f; }
                f32x4 o1; o1.x = nl1.x + nu1.x; o1.y = nl1.y + nu1.y;
                          o1.z = nl1.x - nu1.x; o1.w = nl1.y - nu1.y;
                dst[t + 256] = o1;
            }
            __syncthreads();
        }
    }

    // Epilogue: combine and store (never re-read -> nontemporal).
    const int opix = (h0 + ph) * WW + (w0 + pw);
    const size_t fb = (size_t)opix * SS + jbase + j2 * 2;
    #pragma unroll
    for (int co = 0; co < COUT; ++co) {
        const f32x2 lo = A[co] + B[co];
        const f32x2 uo = A[co] - B[co];
        __builtin_nontemporal_store(lo, (f32x2*)(lx_out + (size_t)co * PLANE + fb));
        __builtin_nontemporal_store(uo, (f32x2*)(ux_out + (size_t)co * PLANE + fb));
    }
}

// Constant-offset conv (tiny: 16*56*56 outputs each).
__global__ __launch_bounds__(256) void ibp_conv_const(
    const float* __restrict__ lc, const float* __restrict__ uc,
    const float* __restrict__ wgt, const float* __restrict__ bias,
    float* __restrict__ lc_out, float* __restrict__ uc_out)
{
    const int idx = blockIdx.x * 256 + threadIdx.x;
    if (idx >= COUT * HH * WW) return;
    const int co  = idx / (HH * WW);
    const int pix = idx - co * (HH * WW);
    const int h = pix / WW, w = pix - (pix / WW) * WW;

    float Aa = 0.f, Bb = 0.f;
    for (int ci = 0; ci < CIN; ++ci) {
        #pragma unroll
        for (int dh = 0; dh < 3; ++dh) {
            const int ih = h + dh - 1;
            if ((unsigned)ih >= (unsigned)HH) continue;
            #pragma unroll
            for (int dw = 0; dw < 3; ++dw) {
                const int iw = w + dw - 1;
                if ((unsigned)iw >= (unsigned)WW) continue;
                const float l = lc[(ci * HH + ih) * WW + iw];
                const float u = uc[(ci * HH + ih) * WW + iw];
                const float wv = wgt[((co * CIN + ci) * 3 + dh) * 3 + dw];
                Aa += wv * (l + u);
                Bb += fabsf(wv) * (l - u);
            }
        }
    }
    const float b = bias[co];
    lc_out[idx] = 0.5f * (Aa + Bb) + b;
    uc_out[idx] = 0.5f * (Aa - Bb) + b;
}

extern "C" void kernel_launch(void* const* d_in, const int* in_sizes, int n_in,
                              void* d_out, int out_size, void* d_ws, size_t ws_size,
                              hipStream_t stream) {
    const float* lx   = (const float*)d_in[0];
    const float* ux   = (const float*)d_in[1];
    const float* lc   = (const float*)d_in[2];
    const float* uc   = (const float*)d_in[3];
    const float* wgt  = (const float*)d_in[4];
    const float* bias = (const float*)d_in[5];

    float* out    = (float*)d_out;
    float* lx_out = out;
    float* ux_out = out + (size_t)SYM_OUT_SZ;
    float* lc_out = out + (size_t)2 * SYM_OUT_SZ;
    float* uc_out = lc_out + COUT * HH * WW;

    float* wtr = (float*)d_ws;   // 72*32 floats = 9216 B

    ibp_prep_w<<<(72 * 16 + 255) / 256, 256, 0, stream>>>(wgt, wtr);

    const int nblk = NCHUNK * (HH / TH) * (WW / TW);   // 49*14*7 = 4802
    ibp_conv_sym<<<nblk, 256, 0, stream>>>(lx, ux, wtr, lx_out, ux_out);

    const int nconst = COUT * HH * WW;
    ibp_conv_const<<<(nconst + 255) / 256, 256, 0, stream>>>(
        lc, uc, wgt, bias, lc_out, uc_out);
}

// Round 5
// 563.209 us; speedup vs baseline: 7.0858x; 7.0858x over previous
//
#include <hip/hip_runtime.h>

#define CIN   8
#define COUT  16
#define HH    56
#define WW    56
#define SS    784                  // 28*28 symbolic vector per pixel
#define PLANE (HH * WW * SS)       // 2458624 floats per channel plane
#define ROW   (WW * SS)            // 43904
#define SYM_OUT_SZ (COUT * PLANE)  // 39337984
#define NJ2   (SS / 2)             // 392 f32x2 units per pixel
#define NPAIR (HH * (WW / 2))      // 1568 horizontal pixel-pairs
#define NTHREADS (NPAIR * NJ2)     // 614656 = 2401 * 256

typedef float f32x2 __attribute__((ext_vector_type(2)));

#if defined(__has_builtin)
#if __has_builtin(__builtin_elementwise_fma)
#define PK_FMA(a, b, c) __builtin_elementwise_fma((a), (b), (c))
#endif
#endif
#ifndef PK_FMA
#define PK_FMA(a, b, c) ((a) * (b) + (c))
#endif

// Prep: transposed weight table in workspace.
// wtr[tap*32 + co]      = 0.5 * w[co][tap]
// wtr[tap*32 + 16 + co] = 0.5 * |w[co][tap]|   (tap = ci*9 + dh*3 + dw)
__global__ __launch_bounds__(256) void ibp_prep_w(
    const float* __restrict__ wgt, float* __restrict__ wtr)
{
    const int i = blockIdx.x * 256 + threadIdx.x;
    if (i >= 72 * 16) return;
    const int tap = i >> 4, co = i & 15;
    const int ci = tap / 9, r = tap - ci * 9;
    const float w = wgt[(co * CIN + ci) * 9 + r];
    wtr[tap * 32 + co]      = 0.5f * w;
    wtr[tap * 32 + 16 + co] = 0.5f * fabsf(w);
}

// Main symbolic-bound conv.
//   lx_out = A + B,  ux_out = A - B   where per tap:
//   A += 0.5*w*(l+u), B += 0.5*|w|*(l-u)
// Each thread owns ONE f32x2 j-lane of TWO adjacent output pixels (w0, w0+1),
// all 16 cout. The pair's 3x3 taps share input columns: 12 (row,col) loads
// per ci instead of 18 -> L3 re-read traffic drops 9x -> 6x and per-output
// address/predication work drops 33%. pk-FMA per output unchanged.
// Weights via uniform scalar loads (SGPR broadcast); no LDS, no barriers.
__global__ __launch_bounds__(256) void ibp_conv_sym(
    const float* __restrict__ lx, const float* __restrict__ ux,
    const float* __restrict__ wtr,
    float* __restrict__ lx_out, float* __restrict__ ux_out)
{
    const int t = threadIdx.x;
    const int b = blockIdx.x;
    // 2401 blocks: chunk 2400 into 8 runs of 300 so XCD k (= b&7 round-robin)
    // walks a contiguous run -> h/w halo reuse stays in that XCD's L2.
    const int vblk = (b < 2400) ? ((b & 7) * 300 + (b >> 3)) : b;
    const int gv   = vblk * 256 + t;

    const int j2 = gv % NJ2;            // f32x2 index within pixel
    const int pp = gv / NJ2;            // pair index
    const int h  = pp / (WW / 2);
    const int wp = pp - h * (WW / 2);
    const int w0 = wp * 2;              // left pixel of the pair
    const int j  = j2 * 2;              // float offset within the 784-vector

    // Column validity + float offsets for input columns w0-1 .. w0+2.
    int cok[4];
    int coff[4];
    #pragma unroll
    for (int c = 0; c < 4; ++c) {
        const int wc = w0 - 1 + c;
        cok[c]  = (unsigned)wc < (unsigned)WW;
        coff[c] = cok[c] ? (wc * SS + j) : 0;
    }

    // Accumulators: 2 pixels x 16 cout x {A,B} f32x2 = 128 VGPRs.
    f32x2 A0[COUT], B0[COUT], A1[COUT], B1[COUT];
    #pragma unroll
    for (int co = 0; co < COUT; ++co) {
        A0[co] = (f32x2)0.f; B0[co] = (f32x2)0.f;
        A1[co] = (f32x2)0.f; B1[co] = (f32x2)0.f;
    }

    for (int ci = 0; ci < CIN; ++ci) {
        const float* lp = lx + (size_t)ci * PLANE;
        const float* up = ux + (size_t)ci * PLANE;
        const float* wci = wtr + ci * 9 * 32;
        #pragma unroll
        for (int dh = 0; dh < 3; ++dh) {
            const int ih = h + dh - 1;
            const bool rv = (unsigned)ih < (unsigned)HH;
            const int rbase = ih * ROW;

            // Load + form s = l+u, d = l-u for the 4 shared columns.
            f32x2 s[4], d[4];
            #pragma unroll
            for (int c = 0; c < 4; ++c) {
                f32x2 lv = (f32x2)0.f, uv = (f32x2)0.f;
                if (rv && cok[c]) {
                    lv = *(const f32x2*)(lp + rbase + coff[c]);
                    uv = *(const f32x2*)(up + rbase + coff[c]);
                }
                s[c] = lv + uv;
                d[c] = lv - uv;
            }

            const float* wt = wci + dh * 3 * 32;  // taps dw=0,1,2 at +0,+32,+64
            #pragma unroll
            for (int co = 0; co < COUT; ++co) {
                const float wa0 = wt[co],       wb0 = wt[16 + co];
                const float wa1 = wt[32 + co],  wb1 = wt[48 + co];
                const float wa2 = wt[64 + co],  wb2 = wt[80 + co];
                const f32x2 a0 = {wa0, wa0}, a1 = {wa1, wa1}, a2 = {wa2, wa2};
                const f32x2 b0 = {wb0, wb0}, b1 = {wb1, wb1}, b2 = {wb2, wb2};
                // out0 (w0):   cols 0,1,2 <-> dw 0,1,2
                A0[co] = PK_FMA(a0, s[0], A0[co]);
                A0[co] = PK_FMA(a1, s[1], A0[co]);
                A0[co] = PK_FMA(a2, s[2], A0[co]);
                B0[co] = PK_FMA(b0, d[0], B0[co]);
                B0[co] = PK_FMA(b1, d[1], B0[co]);
                B0[co] = PK_FMA(b2, d[2], B0[co]);
                // out1 (w0+1): cols 1,2,3 <-> dw 0,1,2
                A1[co] = PK_FMA(a0, s[1], A1[co]);
                A1[co] = PK_FMA(a1, s[2], A1[co]);
                A1[co] = PK_FMA(a2, s[3], A1[co]);
                B1[co] = PK_FMA(b0, d[1], B1[co]);
                B1[co] = PK_FMA(b1, d[2], B1[co]);
                B1[co] = PK_FMA(b2, d[3], B1[co]);
            }
        }
    }

    // Epilogue: combine and store both pixels (never re-read -> nontemporal).
    const size_t fb0 = (size_t)(h * WW + w0) * SS + j;
    const size_t fb1 = fb0 + SS;
    #pragma unroll
    for (int co = 0; co < COUT; ++co) {
        const size_t cb = (size_t)co * PLANE;
        const f32x2 lo0 = A0[co] + B0[co];
        const f32x2 uo0 = A0[co] - B0[co];
        const f32x2 lo1 = A1[co] + B1[co];
        const f32x2 uo1 = A1[co] - B1[co];
        __builtin_nontemporal_store(lo0, (f32x2*)(lx_out + cb + fb0));
        __builtin_nontemporal_store(uo0, (f32x2*)(ux_out + cb + fb0));
        __builtin_nontemporal_store(lo1, (f32x2*)(lx_out + cb + fb1));
        __builtin_nontemporal_store(uo1, (f32x2*)(ux_out + cb + fb1));
    }
}

// Constant-offset conv (tiny: 16*56*56 outputs each).
__global__ __launch_bounds__(256) void ibp_conv_const(
    const float* __restrict__ lc, const float* __restrict__ uc,
    const float* __restrict__ wgt, const float* __restrict__ bias,
    float* __restrict__ lc_out, float* __restrict__ uc_out)
{
    const int idx = blockIdx.x * 256 + threadIdx.x;
    if (idx >= COUT * HH * WW) return;
    const int co  = idx / (HH * WW);
    const int pix = idx - co * (HH * WW);
    const int h = pix / WW, w = pix - (pix / WW) * WW;

    float Aa = 0.f, Bb = 0.f;
    for (int ci = 0; ci < CIN; ++ci) {
        #pragma unroll
        for (int dh = 0; dh < 3; ++dh) {
            const int ih = h + dh - 1;
            if ((unsigned)ih >= (unsigned)HH) continue;
            #pragma unroll
            for (int dw = 0; dw < 3; ++dw) {
                const int iw = w + dw - 1;
                if ((unsigned)iw >= (unsigned)WW) continue;
                const float l = lc[(ci * HH + ih) * WW + iw];
                const float u = uc[(ci * HH + ih) * WW + iw];
                const float wv = wgt[((co * CIN + ci) * 3 + dh) * 3 + dw];
                Aa += wv * (l + u);
                Bb += fabsf(wv) * (l - u);
            }
        }
    }
    const float b = bias[co];
    lc_out[idx] = 0.5f * (Aa + Bb) + b;
    uc_out[idx] = 0.5f * (Aa - Bb) + b;
}

extern "C" void kernel_launch(void* const* d_in, const int* in_sizes, int n_in,
                              void* d_out, int out_size, void* d_ws, size_t ws_size,
                              hipStream_t stream) {
    const float* lx   = (const float*)d_in[0];
    const float* ux   = (const float*)d_in[1];
    const float* lc   = (const float*)d_in[2];
    const float* uc   = (const float*)d_in[3];
    const float* wgt  = (const float*)d_in[4];
    const float* bias = (const float*)d_in[5];

    float* out    = (float*)d_out;
    float* lx_out = out;
    float* ux_out = out + (size_t)SYM_OUT_SZ;
    float* lc_out = out + (size_t)2 * SYM_OUT_SZ;
    float* uc_out = lc_out + COUT * HH * WW;

    float* wtr = (float*)d_ws;   // 72*32 floats = 9216 B

    ibp_prep_w<<<(72 * 16 + 255) / 256, 256, 0, stream>>>(wgt, wtr);

    ibp_conv_sym<<<NTHREADS / 256, 256, 0, stream>>>(lx, ux, wtr, lx_out, ux_out);

    const int nconst = COUT * HH * WW;
    ibp_conv_const<<<(nconst + 255) / 256, 256, 0, stream>>>(
        lc, uc, wgt, bias, lc_out, uc_out);
}

// Round 6
// 537.119 us; speedup vs baseline: 7.4300x; 1.0486x over previous
//
#include <hip/hip_runtime.h>

#define CIN   8
#define COUT  16
#define HH    56
#define WW    56
#define SS    784                  // 28*28 symbolic vector per pixel
#define PLANE (HH * WW * SS)       // 2458624 floats per channel plane
#define ROW   (WW * SS)            // 43904
#define SYM_OUT_SZ (COUT * PLANE)  // 39337984
#define NJ2   (SS / 2)             // 392 f32x2 units per pixel
#define NPAIR (HH * (WW / 2))      // 1568 horizontal pixel-pairs
#define NTHREADS (NPAIR * NJ2)     // 614656 = 2401 * 256

typedef float f32x2 __attribute__((ext_vector_type(2)));

#if defined(__has_builtin)
#if __has_builtin(__builtin_elementwise_fma)
#define PK_FMA(a, b, c) __builtin_elementwise_fma((a), (b), (c))
#endif
#endif
#ifndef PK_FMA
#define PK_FMA(a, b, c) ((a) * (b) + (c))
#endif

// Prep: transposed weight table in workspace.
// wtr[tap*32 + co]      = 0.5 * w[co][tap]
// wtr[tap*32 + 16 + co] = 0.5 * |w[co][tap]|   (tap = ci*9 + dh*3 + dw)
__global__ __launch_bounds__(256) void ibp_prep_w(
    const float* __restrict__ wgt, float* __restrict__ wtr)
{
    const int i = blockIdx.x * 256 + threadIdx.x;
    if (i >= 72 * 16) return;
    const int tap = i >> 4, co = i & 15;
    const int ci = tap / 9, r = tap - ci * 9;
    const float w = wgt[(co * CIN + ci) * 9 + r];
    wtr[tap * 32 + co]      = 0.5f * w;
    wtr[tap * 32 + 16 + co] = 0.5f * fabsf(w);
}

// Inner FMA block shared by both paths: accumulate one (ci,dh) row's 4-column
// s/d values into the 2-pixel x 16-cout accumulators.
#define ROW_FMAS(wt)                                                    \
    do {                                                                \
        _Pragma("unroll")                                               \
        for (int co = 0; co < COUT; ++co) {                             \
            const float wa0 = (wt)[co],      wb0 = (wt)[16 + co];       \
            const float wa1 = (wt)[32 + co], wb1 = (wt)[48 + co];       \
            const float wa2 = (wt)[64 + co], wb2 = (wt)[80 + co];       \
            const f32x2 a0 = {wa0, wa0}, a1 = {wa1, wa1}, a2 = {wa2, wa2}; \
            const f32x2 b0 = {wb0, wb0}, b1 = {wb1, wb1}, b2 = {wb2, wb2}; \
            A0[co] = PK_FMA(a0, s[0], A0[co]);                          \
            A0[co] = PK_FMA(a1, s[1], A0[co]);                          \
            A0[co] = PK_FMA(a2, s[2], A0[co]);                          \
            B0[co] = PK_FMA(b0, d[0], B0[co]);                          \
            B0[co] = PK_FMA(b1, d[1], B0[co]);                          \
            B0[co] = PK_FMA(b2, d[2], B0[co]);                          \
            A1[co] = PK_FMA(a0, s[1], A1[co]);                          \
            A1[co] = PK_FMA(a1, s[2], A1[co]);                          \
            A1[co] = PK_FMA(a2, s[3], A1[co]);                          \
            B1[co] = PK_FMA(b0, d[1], B1[co]);                          \
            B1[co] = PK_FMA(b1, d[2], B1[co]);                          \
            B1[co] = PK_FMA(b2, d[3], B1[co]);                          \
        }                                                               \
    } while (0)

// Main symbolic-bound conv.
//   lx_out = A + B,  ux_out = A - B   where per tap:
//   A += 0.5*w*(l+u), B += 0.5*|w|*(l-u)
// Each thread owns ONE f32x2 j-lane of TWO adjacent output pixels (w0, w0+1),
// all 16 cout; the pair's taps share input columns (12 loads per ci, not 18).
// Interior pairs (h in [1,54], w0 in [2,53]) take a predication-free fast path
// with ci unrolled x2 so next-ci loads issue under current-ci FMAs.
__global__ __launch_bounds__(256) void ibp_conv_sym(
    const float* __restrict__ lx, const float* __restrict__ ux,
    const float* __restrict__ wtr,
    float* __restrict__ lx_out, float* __restrict__ ux_out)
{
    const int t = threadIdx.x;
    const int b = blockIdx.x;
    // 2401 blocks: chunk 2400 into 8 runs of 300 so XCD k (= b&7 round-robin)
    // walks a contiguous run -> h/w halo reuse stays in that XCD's L2.
    const int vblk = (b < 2400) ? ((b & 7) * 300 + (b >> 3)) : b;
    const int gv   = vblk * 256 + t;

    const int j2 = gv % NJ2;            // f32x2 index within pixel
    const int pp = gv / NJ2;            // pair index
    const int h  = pp / (WW / 2);
    const int wp = pp - h * (WW / 2);
    const int w0 = wp * 2;              // left pixel of the pair
    const int j  = j2 * 2;              // float offset within the 784-vector

    // Accumulators: 2 pixels x 16 cout x {A,B} f32x2 = 128 VGPRs.
    f32x2 A0[COUT], B0[COUT], A1[COUT], B1[COUT];
    #pragma unroll
    for (int co = 0; co < COUT; ++co) {
        A0[co] = (f32x2)0.f; B0[co] = (f32x2)0.f;
        A1[co] = (f32x2)0.f; B1[co] = (f32x2)0.f;
    }

    const bool interior = (h >= 1) & (h <= HH - 2) & (wp >= 1) & (wp <= WW / 2 - 2);

    if (interior) {
        // ---------- fast path: no bounds checks, pure base+offset loads ----
        // base of (row ih=h-1, col w0-1) in floats; row step ROW, col step SS.
        const size_t base = (size_t)((h - 1) * WW + (w0 - 1)) * SS + j;
        const float* lp0 = lx + base;
        const float* up0 = ux + base;

        #pragma unroll 2
        for (int ci = 0; ci < CIN; ++ci) {
            const float* lp = lp0 + (size_t)ci * PLANE;
            const float* up = up0 + (size_t)ci * PLANE;
            const float* wci = wtr + ci * 9 * 32;
            #pragma unroll
            for (int dh = 0; dh < 3; ++dh) {
                const float* rl = lp + dh * ROW;
                const float* ru = up + dh * ROW;
                f32x2 s[4], d[4];
                #pragma unroll
                for (int c = 0; c < 4; ++c) {
                    const f32x2 lv = *(const f32x2*)(rl + c * SS);
                    const f32x2 uv = *(const f32x2*)(ru + c * SS);
                    s[c] = lv + uv;
                    d[c] = lv - uv;
                }
                const float* wt = wci + dh * 3 * 32;
                ROW_FMAS(wt);
            }
        }
    } else {
        // ---------- general path: per-column validity (round-5 logic) ------
        int cok[4];
        int coff[4];
        #pragma unroll
        for (int c = 0; c < 4; ++c) {
            const int wc = w0 - 1 + c;
            cok[c]  = (unsigned)wc < (unsigned)WW;
            coff[c] = cok[c] ? (wc * SS + j) : 0;
        }
        for (int ci = 0; ci < CIN; ++ci) {
            const float* lp = lx + (size_t)ci * PLANE;
            const float* up = ux + (size_t)ci * PLANE;
            const float* wci = wtr + ci * 9 * 32;
            #pragma unroll
            for (int dh = 0; dh < 3; ++dh) {
                const int ih = h + dh - 1;
                const bool rv = (unsigned)ih < (unsigned)HH;
                const int rbase = ih * ROW;
                f32x2 s[4], d[4];
                #pragma unroll
                for (int c = 0; c < 4; ++c) {
                    f32x2 lv = (f32x2)0.f, uv = (f32x2)0.f;
                    if (rv && cok[c]) {
                        lv = *(const f32x2*)(lp + rbase + coff[c]);
                        uv = *(const f32x2*)(up + rbase + coff[c]);
                    }
                    s[c] = lv + uv;
                    d[c] = lv - uv;
                }
                const float* wt = wci + dh * 3 * 32;
                ROW_FMAS(wt);
            }
        }
    }

    // Epilogue: combine and store both pixels (never re-read -> nontemporal).
    const size_t fb0 = (size_t)(h * WW + w0) * SS + j;
    const size_t fb1 = fb0 + SS;
    #pragma unroll
    for (int co = 0; co < COUT; ++co) {
        const size_t cb = (size_t)co * PLANE;
        const f32x2 lo0 = A0[co] + B0[co];
        const f32x2 uo0 = A0[co] - B0[co];
        const f32x2 lo1 = A1[co] + B1[co];
        const f32x2 uo1 = A1[co] - B1[co];
        __builtin_nontemporal_store(lo0, (f32x2*)(lx_out + cb + fb0));
        __builtin_nontemporal_store(uo0, (f32x2*)(ux_out + cb + fb0));
        __builtin_nontemporal_store(lo1, (f32x2*)(lx_out + cb + fb1));
        __builtin_nontemporal_store(uo1, (f32x2*)(ux_out + cb + fb1));
    }
}

// Constant-offset conv (tiny: 16*56*56 outputs each).
__global__ __launch_bounds__(256) void ibp_conv_const(
    const float* __restrict__ lc, const float* __restrict__ uc,
    const float* __restrict__ wgt, const float* __restrict__ bias,
    float* __restrict__ lc_out, float* __restrict__ uc_out)
{
    const int idx = blockIdx.x * 256 + threadIdx.x;
    if (idx >= COUT * HH * WW) return;
    const int co  = idx / (HH * WW);
    const int pix = idx - co * (HH * WW);
    const int h = pix / WW, w = pix - (pix / WW) * WW;

    float Aa = 0.f, Bb = 0.f;
    for (int ci = 0; ci < CIN; ++ci) {
        #pragma unroll
        for (int dh = 0; dh < 3; ++dh) {
            const int ih = h + dh - 1;
            if ((unsigned)ih >= (unsigned)HH) continue;
            #pragma unroll
            for (int dw = 0; dw < 3; ++dw) {
                const int iw = w + dw - 1;
                if ((unsigned)iw >= (unsigned)WW) continue;
                const float l = lc[(ci * HH + ih) * WW + iw];
                const float u = uc[(ci * HH + ih) * WW + iw];
                const float wv = wgt[((co * CIN + ci) * 3 + dh) * 3 + dw];
                Aa += wv * (l + u);
                Bb += fabsf(wv) * (l - u);
            }
        }
    }
    const float b = bias[co];
    lc_out[idx] = 0.5f * (Aa + Bb) + b;
    uc_out[idx] = 0.5f * (Aa - Bb) + b;
}

extern "C" void kernel_launch(void* const* d_in, const int* in_sizes, int n_in,
                              void* d_out, int out_size, void* d_ws, size_t ws_size,
                              hipStream_t stream) {
    const float* lx   = (const float*)d_in[0];
    const float* ux   = (const float*)d_in[1];
    const float* lc   = (const float*)d_in[2];
    const float* uc   = (const float*)d_in[3];
    const float* wgt  = (const float*)d_in[4];
    const float* bias = (const float*)d_in[5];

    float* out    = (float*)d_out;
    float* lx_out = out;
    float* ux_out = out + (size_t)SYM_OUT_SZ;
    float* lc_out = out + (size_t)2 * SYM_OUT_SZ;
    float* uc_out = lc_out + COUT * HH * WW;

    float* wtr = (float*)d_ws;   // 72*32 floats = 9216 B

    ibp_prep_w<<<(72 * 16 + 255) / 256, 256, 0, stream>>>(wgt, wtr);

    ibp_conv_sym<<<NTHREADS / 256, 256, 0, stream>>>(lx, ux, wtr, lx_out, ux_out);

    const int nconst = COUT * HH * WW;
    ibp_conv_const<<<(nconst + 255) / 256, 256, 0, stream>>>(
        lc, uc, wgt, bias, lc_out, uc_out);
}